// Round 6
// baseline (166.807 us; speedup 1.0000x reference)
//
#include <hip/hip_runtime.h>
#include <hip/hip_bf16.h>
#include <cstdint>

typedef __attribute__((ext_vector_type(4))) float f32x4;
typedef __attribute__((ext_vector_type(8))) short short8;

#define DEVI __device__ __forceinline__

// float -> bf16 with round-to-nearest-even
DEVI uint16_t f2bf(float v) {
    union { float f; uint32_t u; } c; c.f = v;
    uint32_t u = c.u + 0x7FFFu + ((c.u >> 16) & 1u);
    return (uint16_t)(u >> 16);
}
DEVI float bflo(uint32_t u) { union { uint32_t u; float f; } c; c.u = u << 16; return c.f; }
DEVI float bfhi(uint32_t u) { union { uint32_t u; float f; } c; c.u = u & 0xFFFF0000u; return c.f; }

// async global->LDS, 16 bytes per lane
DEVI void async16(const uint16_t* g, uint16_t* l) {
    __builtin_amdgcn_global_load_lds((const __attribute__((address_space(1))) void*)g,
                                     (__attribute__((address_space(3))) void*)l, 16, 0, 0);
}

// ---------------- out init: out[m][j] = b3[j] ----------------
__global__ __launch_bounds__(256) void init_out(float* __restrict__ out, const float* __restrict__ b3) {
    const int i = blockIdx.x * 256 + threadIdx.x;      // 8192 threads, one row each
    float4 b = { b3[0], b3[1], b3[2], b3[3] };
    ((float4*)out)[i] = b;
}

// ---------------- merged prep: feat transpose (blocks 0..127) + weight cvt (blocks 128..1151) ----------------
__global__ __launch_bounds__(256) void prep_all(const float* __restrict__ f, uint16_t* __restrict__ featT,
                                                const float* __restrict__ W1, uint16_t* __restrict__ W1b,
                                                const float* __restrict__ W2, uint16_t* __restrict__ W2b) {
    if (blockIdx.x < 128) {
        __shared__ uint16_t s[128 * 130];   // pad 130 to break bank conflicts on transpose
        const int x = blockIdx.x;           // H index
        const float* fx = f + x * 128;      // f[c*16384 + x*128 + y]
        for (int i = threadIdx.x; i < 16384; i += 256) {
            int c = i >> 7, y = i & 127;
            s[y * 130 + c] = f2bf(fx[c * 16384 + y]);
        }
        __syncthreads();
        uint16_t* o = featT + x * 16384;    // featT[(x*128 + y)*128 + c]
        for (int i = threadIdx.x; i < 16384; i += 256) {
            int y = i >> 7, c = i & 127;
            o[i] = s[y * 130 + c];
        }
    } else {
        const int i = (blockIdx.x - 128) * 256 + threadIdx.x;   // 262144 threads x 4 elems
        float4 a = ((const float4*)W1)[i];
        float4 b = ((const float4*)W2)[i];
        ushort4 pa = { f2bf(a.x), f2bf(a.y), f2bf(a.z), f2bf(a.w) };
        ushort4 pb = { f2bf(b.x), f2bf(b.y), f2bf(b.z), f2bf(b.w) };
        ((ushort4*)W1b)[i] = pa;
        ((ushort4*)W2b)[i] = pb;
    }
}

// ---------------- extract + bilinear + maxpool(4) -> flat (8192 x 1024) bf16 ----------------
__global__ __launch_bounds__(256) void extract_k(const float4* __restrict__ lines,
                                                 const uint16_t* __restrict__ featT,
                                                 uint16_t* __restrict__ flat) {
    const int n = blockIdx.x;
    const int tid = threadIdx.x;
    const int lane = tid & 63, wave = tid >> 6;
    const float4 ln = lines[n];           // (U.x, U.y, V.x, V.y)
    __shared__ uint16_t ps[1024];
    const uint16_t* fb = featT + lane * 2;     // channels 2*lane, 2*lane+1

    for (int g2 = 0; g2 < 2; ++g2) {
        const int g = wave * 2 + g2;           // pool group 0..7
        float m0 = -1e30f, m1 = -1e30f;
#pragma unroll
        for (int pp = 0; pp < 4; ++pp) {
            const float t = (float)(g * 4 + pp) * (1.0f / 31.0f);
            const float x = ln.x * t + ln.z * (1.0f - t) - 0.5f;   // indexes H
            const float y = ln.y * t + ln.w * (1.0f - t) - 0.5f;   // indexes W
            const float x0f = fminf(fmaxf(floorf(x), 0.0f), 127.0f);
            const float y0f = fminf(fmaxf(floorf(y), 0.0f), 127.0f);
            const float x1f = fminf(x0f + 1.0f, 127.0f);
            const float y1f = fminf(y0f + 1.0f, 127.0f);
            const int x0 = (int)x0f, x1 = (int)x1f, y0 = (int)y0f, y1 = (int)y1f;
            const float wx1 = x - x0f, wx0 = x1f - x;
            const float wy1 = y - y0f, wy0 = y1f - y;
            const uint32_t u00 = *(const uint32_t*)(fb + ((x0 * 128 + y0) << 7));
            const uint32_t u01 = *(const uint32_t*)(fb + ((x0 * 128 + y1) << 7));
            const uint32_t u10 = *(const uint32_t*)(fb + ((x1 * 128 + y0) << 7));
            const uint32_t u11 = *(const uint32_t*)(fb + ((x1 * 128 + y1) << 7));
            const float w00 = wy0 * wx0, w01 = wy1 * wx0, w10 = wy0 * wx1, w11 = wy1 * wx1;
            const float a = bflo(u00) * w00 + bflo(u01) * w01 + bflo(u10) * w10 + bflo(u11) * w11;
            const float b = bfhi(u00) * w00 + bfhi(u01) * w01 + bfhi(u10) * w10 + bfhi(u11) * w11;
            m0 = fmaxf(m0, a);
            m1 = fmaxf(m1, b);
        }
        ps[lane * 16 + g]     = f2bf(m0);   // channel 2*lane
        ps[lane * 16 + 8 + g] = f2bf(m1);   // channel 2*lane+1
    }
    __syncthreads();
    // coalesced 2KB row write
    *(uint2*)(flat + (size_t)n * 1024 + tid * 4) = ((const uint2*)ps)[tid];
}

// ---------------- bf16 GEMM: round-2 sync structure, 64x128 tile -> grid 1024 = 4 blocks/CU ----------
// FUSE3=0: Co[m][n] = relu(sum_k A[m][k]*B[n][k] + bias[n])  (bf16 store)
// FUSE3=1: out3[m][j] += sum_n relu(...)[m][n] * W3[j][n]    (fp32 atomics; out3 pre-init with b3)
// Tile: 64 rows x 128 cols. 4 waves; wave w owns all 64 rows x cols [w*32, w*32+32): acc[4][2].
template <int FUSE3>
__global__ __launch_bounds__(256) void gemm_bt(const uint16_t* __restrict__ A,
                                               const uint16_t* __restrict__ B,
                                               const float* __restrict__ bias,
                                               uint16_t* __restrict__ Co,
                                               const float* __restrict__ W3,
                                               float* __restrict__ out3,
                                               int M, int N, int K) {
    __shared__ uint16_t As[64 * 32];    // 4 KB
    __shared__ uint16_t Bs[128 * 32];   // 8 KB
    const int tid = threadIdx.x;
    const int lane = tid & 63, wave = tid >> 6;
    const int nbm = M >> 6;                        // 128
    const int bm = blockIdx.x % nbm;               // same-bm partners stride 128 (==0 mod 8): same XCD
    const int bn = blockIdx.x / nbm;
    const int l15 = lane & 15, l16 = lane >> 4;

    f32x4 acc[4][2] = {};

    const uint16_t* Ag = A + (size_t)(bm * 64) * K;
    const uint16_t* Bg = B + (size_t)(bn * 128) * K;

    for (int kt = 0; kt < K; kt += 32) {
        if (kt) __syncthreads();
        {   // A: 256 chunks of 16B (64 rows x 4 chunks); B: 512 chunks (128 rows x 4)
            const int arow = tid >> 2, aoff = (tid & 3) * 8;
            async16(Ag + (size_t)arow * K + kt + aoff, &As[tid * 8]);
#pragma unroll
            for (int i = 0; i < 2; ++i) {
                const int c = i * 256 + tid;
                const int row = c >> 2, off = (c & 3) * 8;
                async16(Bg + (size_t)row * K + kt + off, &Bs[c * 8]);
            }
        }
        __syncthreads();
        short8 a[4], b[2];
#pragma unroll
        for (int fm = 0; fm < 4; ++fm)
            a[fm] = *(const short8*)&As[(fm * 16 + l15) * 32 + l16 * 8];
#pragma unroll
        for (int fn = 0; fn < 2; ++fn)
            b[fn] = *(const short8*)&Bs[(wave * 32 + fn * 16 + l15) * 32 + l16 * 8];
#pragma unroll
        for (int fm = 0; fm < 4; ++fm)
#pragma unroll
            for (int fn = 0; fn < 2; ++fn)
                acc[fm][fn] = __builtin_amdgcn_mfma_f32_16x16x32_bf16(a[fm], b[fn], acc[fm][fn], 0, 0, 0);
    }

    if (!FUSE3) {
#pragma unroll
        for (int fm = 0; fm < 4; ++fm) {
            const int row = bm * 64 + fm * 16 + l16 * 4;
#pragma unroll
            for (int fn = 0; fn < 2; ++fn) {
                const int col = bn * 128 + wave * 32 + fn * 16 + l15;
                const float bv = bias[col];
#pragma unroll
                for (int r = 0; r < 4; ++r) {
                    float v = fmaxf(acc[fm][fn][r] + bv, 0.0f);
                    Co[(size_t)(row + r) * N + col] = f2bf(v);
                }
            }
        }
    } else {
        float bv[2], w3v[4][2];
#pragma unroll
        for (int fn = 0; fn < 2; ++fn) {
            const int col = bn * 128 + wave * 32 + fn * 16 + l15;
            bv[fn] = bias[col];
#pragma unroll
            for (int j = 0; j < 4; ++j) w3v[j][fn] = W3[j * N + col];
        }
#pragma unroll
        for (int fm = 0; fm < 4; ++fm) {
            const int row = bm * 64 + fm * 16 + l16 * 4;
#pragma unroll
            for (int r = 0; r < 4; ++r) {
                float p[4] = { 0.0f, 0.0f, 0.0f, 0.0f };
#pragma unroll
                for (int fn = 0; fn < 2; ++fn) {
                    const float hv = fmaxf(acc[fm][fn][r] + bv[fn], 0.0f);
#pragma unroll
                    for (int j = 0; j < 4; ++j) p[j] += hv * w3v[j][fn];
                }
#pragma unroll
                for (int off = 1; off <= 8; off <<= 1)
#pragma unroll
                    for (int j = 0; j < 4; ++j) p[j] += __shfl_xor(p[j], off);
                if (l15 == 0) {
                    float* o = out3 + (size_t)(row + r) * 4;
#pragma unroll
                    for (int j = 0; j < 4; ++j) atomicAdd(o + j, p[j]);
                }
            }
        }
    }
}

extern "C" void kernel_launch(void* const* d_in, const int* in_sizes, int n_in,
                              void* d_out, int out_size, void* d_ws, size_t ws_size,
                              hipStream_t stream) {
    const float* feats = (const float*)d_in[0];   // 128*128*128 (C,H,W)
    const float* lines = (const float*)d_in[1];   // 8192*4
    const float* W1 = (const float*)d_in[2];      // 1024*1024
    const float* b1 = (const float*)d_in[3];
    const float* W2 = (const float*)d_in[4];
    const float* b2 = (const float*)d_in[5];
    const float* W3 = (const float*)d_in[6];      // 4*1024
    const float* b3 = (const float*)d_in[7];
    float* out = (float*)d_out;

    char* ws = (char*)d_ws;
    uint16_t* featT = (uint16_t*)(ws);                        // 4 MB  (H,W,C) bf16
    uint16_t* W1b   = (uint16_t*)(ws + (4u << 20));           // 2 MB
    uint16_t* W2b   = (uint16_t*)(ws + (6u << 20));           // 2 MB
    uint16_t* flat  = (uint16_t*)(ws + (8u << 20));           // 16 MB
    uint16_t* h1    = (uint16_t*)(ws + (24u << 20));          // 16 MB -> total 40 MB

    init_out<<<32, 256, 0, stream>>>(out, b3);
    prep_all<<<1152, 256, 0, stream>>>(feats, featT, W1, W1b, W2, W2b);
    extract_k<<<8192, 256, 0, stream>>>((const float4*)lines, featT, flat);
    gemm_bt<0><<<1024, 256, 0, stream>>>(flat, W1b, b1, h1, nullptr, nullptr, 8192, 1024, 1024);
    gemm_bt<1><<<1024, 256, 0, stream>>>(h1, W2b, b2, nullptr, W3, out, 8192, 1024, 1024);
}

// Round 7
// 118.027 us; speedup vs baseline: 1.4133x; 1.4133x over previous
//
#include <hip/hip_runtime.h>
#include <hip/hip_bf16.h>
#include <cstdint>

typedef __attribute__((ext_vector_type(4))) float f32x4;
typedef __attribute__((ext_vector_type(8))) short short8;

#define DEVI __device__ __forceinline__

// float -> bf16 with round-to-nearest-even
DEVI uint16_t f2bf(float v) {
    union { float f; uint32_t u; } c; c.f = v;
    uint32_t u = c.u + 0x7FFFu + ((c.u >> 16) & 1u);
    return (uint16_t)(u >> 16);
}
DEVI float bflo(uint32_t u) { union { uint32_t u; float f; } c; c.u = u << 16; return c.f; }
DEVI float bfhi(uint32_t u) { union { uint32_t u; float f; } c; c.u = u & 0xFFFF0000u; return c.f; }

// async global->LDS, 16 bytes per lane
DEVI void async16(const uint16_t* g, uint16_t* l) {
    __builtin_amdgcn_global_load_lds((const __attribute__((address_space(1))) void*)g,
                                     (__attribute__((address_space(3))) void*)l, 16, 0, 0);
}

// ---------------- out init: out[m][j] = b3[j] ----------------
__global__ __launch_bounds__(256) void init_out(float* __restrict__ out, const float* __restrict__ b3) {
    const int i = blockIdx.x * 256 + threadIdx.x;      // 8192 threads, one row each
    float4 b = { b3[0], b3[1], b3[2], b3[3] };
    ((float4*)out)[i] = b;
}

// ---------------- merged prep: feat transpose (blocks 0..127) + weight cvt (blocks 128..1151) ----------------
__global__ __launch_bounds__(256) void prep_all(const float* __restrict__ f, uint16_t* __restrict__ featT,
                                                const float* __restrict__ W1, uint16_t* __restrict__ W1b,
                                                const float* __restrict__ W2, uint16_t* __restrict__ W2b) {
    if (blockIdx.x < 128) {
        __shared__ uint16_t s[128 * 130];   // pad 130 to break bank conflicts on transpose
        const int x = blockIdx.x;           // H index
        const float* fx = f + x * 128;      // f[c*16384 + x*128 + y]
        for (int i = threadIdx.x; i < 16384; i += 256) {
            int c = i >> 7, y = i & 127;
            s[y * 130 + c] = f2bf(fx[c * 16384 + y]);
        }
        __syncthreads();
        uint16_t* o = featT + x * 16384;    // featT[(x*128 + y)*128 + c]
        for (int i = threadIdx.x; i < 16384; i += 256) {
            int y = i >> 7, c = i & 127;
            o[i] = s[y * 130 + c];
        }
    } else {
        const int i = (blockIdx.x - 128) * 256 + threadIdx.x;   // 262144 threads x 4 elems
        float4 a = ((const float4*)W1)[i];
        float4 b = ((const float4*)W2)[i];
        ushort4 pa = { f2bf(a.x), f2bf(a.y), f2bf(a.z), f2bf(a.w) };
        ushort4 pb = { f2bf(b.x), f2bf(b.y), f2bf(b.z), f2bf(b.w) };
        ((ushort4*)W1b)[i] = pa;
        ((ushort4*)W2b)[i] = pb;
    }
}

// ---------------- extract + bilinear + maxpool(4) -> flat (8192 x 1024) bf16 ----------------
__global__ __launch_bounds__(256) void extract_k(const float4* __restrict__ lines,
                                                 const uint16_t* __restrict__ featT,
                                                 uint16_t* __restrict__ flat) {
    const int n = blockIdx.x;
    const int tid = threadIdx.x;
    const int lane = tid & 63, wave = tid >> 6;
    const float4 ln = lines[n];           // (U.x, U.y, V.x, V.y)
    __shared__ uint16_t ps[1024];
    const uint16_t* fb = featT + lane * 2;     // channels 2*lane, 2*lane+1

    for (int g2 = 0; g2 < 2; ++g2) {
        const int g = wave * 2 + g2;           // pool group 0..7
        float m0 = -1e30f, m1 = -1e30f;
#pragma unroll
        for (int pp = 0; pp < 4; ++pp) {
            const float t = (float)(g * 4 + pp) * (1.0f / 31.0f);
            const float x = ln.x * t + ln.z * (1.0f - t) - 0.5f;   // indexes H
            const float y = ln.y * t + ln.w * (1.0f - t) - 0.5f;   // indexes W
            const float x0f = fminf(fmaxf(floorf(x), 0.0f), 127.0f);
            const float y0f = fminf(fmaxf(floorf(y), 0.0f), 127.0f);
            const float x1f = fminf(x0f + 1.0f, 127.0f);
            const float y1f = fminf(y0f + 1.0f, 127.0f);
            const int x0 = (int)x0f, x1 = (int)x1f, y0 = (int)y0f, y1 = (int)y1f;
            const float wx1 = x - x0f, wx0 = x1f - x;
            const float wy1 = y - y0f, wy0 = y1f - y;
            const uint32_t u00 = *(const uint32_t*)(fb + ((x0 * 128 + y0) << 7));
            const uint32_t u01 = *(const uint32_t*)(fb + ((x0 * 128 + y1) << 7));
            const uint32_t u10 = *(const uint32_t*)(fb + ((x1 * 128 + y0) << 7));
            const uint32_t u11 = *(const uint32_t*)(fb + ((x1 * 128 + y1) << 7));
            const float w00 = wy0 * wx0, w01 = wy1 * wx0, w10 = wy0 * wx1, w11 = wy1 * wx1;
            const float a = bflo(u00) * w00 + bflo(u01) * w01 + bflo(u10) * w10 + bflo(u11) * w11;
            const float b = bfhi(u00) * w00 + bfhi(u01) * w01 + bfhi(u10) * w10 + bfhi(u11) * w11;
            m0 = fmaxf(m0, a);
            m1 = fmaxf(m1, b);
        }
        ps[lane * 16 + g]     = f2bf(m0);   // channel 2*lane
        ps[lane * 16 + 8 + g] = f2bf(m1);   // channel 2*lane+1
    }
    __syncthreads();
    // coalesced 2KB row write
    *(uint2*)(flat + (size_t)n * 1024 + tid * 4) = ((const uint2*)ps)[tid];
}

// ---------------- bf16 GEMM: R2-exact structure (BK=32, 128x128, 2 barriers/iter) ----------------
// + 2-bit chunk-XOR swizzle g(r)=(r>>1)&3 as involution on stage-source and ds_read slot
// (kills the ~4-way temporal bank conflict; coalescing intact: permutation stays within each 64B row).
// FUSE3=0: Co[m][n] = relu(sum_k A[m][k]*B[n][k] + bias[n])  (bf16 store)
// FUSE3=1: out3[m][j] += sum_n relu(...)[m][n] * W3[j][n]    (fp32 atomics; out3 pre-init with b3)
template <int FUSE3>
__global__ __launch_bounds__(256) void gemm_bt(const uint16_t* __restrict__ A,
                                               const uint16_t* __restrict__ B,
                                               const float* __restrict__ bias,
                                               uint16_t* __restrict__ Co,
                                               const float* __restrict__ W3,
                                               float* __restrict__ out3,
                                               int M, int N, int K) {
    __shared__ uint16_t As[128 * 32];
    __shared__ uint16_t Bs[128 * 32];
    const int tid = threadIdx.x;
    const int lane = tid & 63, wave = tid >> 6;
    const int nbm = M >> 7;
    const int bm = blockIdx.x % nbm;      // bn-partners stride 64 (==0 mod 8): same XCD
    const int bn = blockIdx.x / nbm;
    const int wr = wave >> 1, wc = wave & 1;       // 2x2 waves, each 64x64
    const int l15 = lane & 15, l16 = lane >> 4;

    f32x4 acc[4][4] = {};

    const uint16_t* Ag = A + (size_t)(bm * 128) * K;
    const uint16_t* Bg = B + (size_t)(bn * 128) * K;

    for (int kt = 0; kt < K; kt += 32) {
        if (kt) __syncthreads();
#pragma unroll
        for (int i = 0; i < 2; ++i) {
            const int c = i * 256 + tid;           // 16B chunk 0..511; 4 chunks (slots) per 64B row
            const int row = c >> 2, slot = c & 3;
            const int src = slot ^ ((row >> 1) & 3);   // LDS slot holds global chunk src (involution)
            async16(Ag + (size_t)row * K + kt + src * 8, &As[c * 8]);
            async16(Bg + (size_t)row * K + kt + src * 8, &Bs[c * 8]);
        }
        __syncthreads();
        short8 a[4], b[4];
#pragma unroll
        for (int fm = 0; fm < 4; ++fm) {
            const int r = wr * 64 + fm * 16 + l15;
            a[fm] = *(const short8*)&As[r * 32 + (l16 ^ ((r >> 1) & 3)) * 8];
        }
#pragma unroll
        for (int fn = 0; fn < 4; ++fn) {
            const int r = wc * 64 + fn * 16 + l15;
            b[fn] = *(const short8*)&Bs[r * 32 + (l16 ^ ((r >> 1) & 3)) * 8];
        }
#pragma unroll
        for (int fm = 0; fm < 4; ++fm)
#pragma unroll
            for (int fn = 0; fn < 4; ++fn)
                acc[fm][fn] = __builtin_amdgcn_mfma_f32_16x16x32_bf16(a[fm], b[fn], acc[fm][fn], 0, 0, 0);
    }

    if (!FUSE3) {
#pragma unroll
        for (int fm = 0; fm < 4; ++fm) {
            const int row = bm * 128 + wr * 64 + fm * 16 + l16 * 4;
#pragma unroll
            for (int fn = 0; fn < 4; ++fn) {
                const int col = bn * 128 + wc * 64 + fn * 16 + l15;
                const float bv = bias[col];
#pragma unroll
                for (int r = 0; r < 4; ++r) {
                    float v = fmaxf(acc[fm][fn][r] + bv, 0.0f);
                    Co[(size_t)(row + r) * N + col] = f2bf(v);
                }
            }
        }
    } else {
        float bv[4], w3v[4][4];
#pragma unroll
        for (int fn = 0; fn < 4; ++fn) {
            const int col = bn * 128 + wc * 64 + fn * 16 + l15;
            bv[fn] = bias[col];
#pragma unroll
            for (int j = 0; j < 4; ++j) w3v[j][fn] = W3[j * N + col];
        }
#pragma unroll
        for (int fm = 0; fm < 4; ++fm) {
            const int row = bm * 128 + wr * 64 + fm * 16 + l16 * 4;
#pragma unroll
            for (int r = 0; r < 4; ++r) {
                float p[4] = { 0.0f, 0.0f, 0.0f, 0.0f };
#pragma unroll
                for (int fn = 0; fn < 4; ++fn) {
                    const float hv = fmaxf(acc[fm][fn][r] + bv[fn], 0.0f);
#pragma unroll
                    for (int j = 0; j < 4; ++j) p[j] += hv * w3v[j][fn];
                }
#pragma unroll
                for (int off = 1; off <= 8; off <<= 1)
#pragma unroll
                    for (int j = 0; j < 4; ++j) p[j] += __shfl_xor(p[j], off);
                if (l15 == 0) {
                    float* o = out3 + (size_t)(row + r) * 4;
#pragma unroll
                    for (int j = 0; j < 4; ++j) atomicAdd(o + j, p[j]);
                }
            }
        }
    }
}

extern "C" void kernel_launch(void* const* d_in, const int* in_sizes, int n_in,
                              void* d_out, int out_size, void* d_ws, size_t ws_size,
                              hipStream_t stream) {
    const float* feats = (const float*)d_in[0];   // 128*128*128 (C,H,W)
    const float* lines = (const float*)d_in[1];   // 8192*4
    const float* W1 = (const float*)d_in[2];      // 1024*1024
    const float* b1 = (const float*)d_in[3];
    const float* W2 = (const float*)d_in[4];
    const float* b2 = (const float*)d_in[5];
    const float* W3 = (const float*)d_in[6];      // 4*1024
    const float* b3 = (const float*)d_in[7];
    float* out = (float*)d_out;

    char* ws = (char*)d_ws;
    uint16_t* featT = (uint16_t*)(ws);                        // 4 MB  (H,W,C) bf16
    uint16_t* W1b   = (uint16_t*)(ws + (4u << 20));           // 2 MB
    uint16_t* W2b   = (uint16_t*)(ws + (6u << 20));           // 2 MB
    uint16_t* flat  = (uint16_t*)(ws + (8u << 20));           // 16 MB
    uint16_t* h1    = (uint16_t*)(ws + (24u << 20));          // 16 MB -> total 40 MB

    init_out<<<32, 256, 0, stream>>>(out, b3);
    prep_all<<<1152, 256, 0, stream>>>(feats, featT, W1, W1b, W2, W2b);
    extract_k<<<8192, 256, 0, stream>>>((const float4*)lines, featT, flat);
    gemm_bt<0><<<512, 256, 0, stream>>>(flat, W1b, b1, h1, nullptr, nullptr, 8192, 1024, 1024);
    gemm_bt<1><<<512, 256, 0, stream>>>(h1, W2b, b2, nullptr, W3, out, 8192, 1024, 1024);
}

// Round 8
// 115.280 us; speedup vs baseline: 1.4470x; 1.0238x over previous
//
#include <hip/hip_runtime.h>
#include <hip/hip_bf16.h>
#include <cstdint>

typedef __attribute__((ext_vector_type(4))) float f32x4;
typedef __attribute__((ext_vector_type(8))) short short8;

#define DEVI __device__ __forceinline__

// float -> bf16 with round-to-nearest-even
DEVI uint16_t f2bf(float v) {
    union { float f; uint32_t u; } c; c.f = v;
    uint32_t u = c.u + 0x7FFFu + ((c.u >> 16) & 1u);
    return (uint16_t)(u >> 16);
}
DEVI float bflo(uint32_t u) { union { uint32_t u; float f; } c; c.u = u << 16; return c.f; }
DEVI float bfhi(uint32_t u) { union { uint32_t u; float f; } c; c.u = u & 0xFFFF0000u; return c.f; }

// async global->LDS, 16 bytes per lane
DEVI void async16(const uint16_t* g, uint16_t* l) {
    __builtin_amdgcn_global_load_lds((const __attribute__((address_space(1))) void*)g,
                                     (__attribute__((address_space(3))) void*)l, 16, 0, 0);
}

// ---------------- out init: out[m][j] = b3[j] ----------------
__global__ __launch_bounds__(256) void init_out(float* __restrict__ out, const float* __restrict__ b3) {
    const int i = blockIdx.x * 256 + threadIdx.x;      // 8192 threads, one row each
    float4 b = { b3[0], b3[1], b3[2], b3[3] };
    ((float4*)out)[i] = b;
}

// ---------------- merged prep: feat transpose (blocks 0..127) + weight cvt (blocks 128..1151) ----------------
__global__ __launch_bounds__(256) void prep_all(const float* __restrict__ f, uint16_t* __restrict__ featT,
                                                const float* __restrict__ W1, uint16_t* __restrict__ W1b,
                                                const float* __restrict__ W2, uint16_t* __restrict__ W2b) {
    if (blockIdx.x < 128) {
        __shared__ uint16_t s[128 * 130];   // pad 130 to break bank conflicts on transpose
        const int x = blockIdx.x;           // H index
        const float* fx = f + x * 128;      // f[c*16384 + x*128 + y]
        for (int i = threadIdx.x; i < 16384; i += 256) {
            int c = i >> 7, y = i & 127;
            s[y * 130 + c] = f2bf(fx[c * 16384 + y]);
        }
        __syncthreads();
        uint16_t* o = featT + x * 16384;    // featT[(x*128 + y)*128 + c]
        for (int i = threadIdx.x; i < 16384; i += 256) {
            int y = i >> 7, c = i & 127;
            o[i] = s[y * 130 + c];
        }
    } else {
        const int i = (blockIdx.x - 128) * 256 + threadIdx.x;   // 262144 threads x 4 elems
        float4 a = ((const float4*)W1)[i];
        float4 b = ((const float4*)W2)[i];
        ushort4 pa = { f2bf(a.x), f2bf(a.y), f2bf(a.z), f2bf(a.w) };
        ushort4 pb = { f2bf(b.x), f2bf(b.y), f2bf(b.z), f2bf(b.w) };
        ((ushort4*)W1b)[i] = pa;
        ((ushort4*)W2b)[i] = pb;
    }
}

// ---------------- extract + bilinear + maxpool(4) -> flat (8192 x 1024) bf16 ----------------
__global__ __launch_bounds__(256) void extract_k(const float4* __restrict__ lines,
                                                 const uint16_t* __restrict__ featT,
                                                 uint16_t* __restrict__ flat) {
    const int n = blockIdx.x;
    const int tid = threadIdx.x;
    const int lane = tid & 63, wave = tid >> 6;
    const float4 ln = lines[n];           // (U.x, U.y, V.x, V.y)
    __shared__ uint16_t ps[1024];
    const uint16_t* fb = featT + lane * 2;     // channels 2*lane, 2*lane+1

    for (int g2 = 0; g2 < 2; ++g2) {
        const int g = wave * 2 + g2;           // pool group 0..7
        float m0 = -1e30f, m1 = -1e30f;
#pragma unroll
        for (int pp = 0; pp < 4; ++pp) {
            const float t = (float)(g * 4 + pp) * (1.0f / 31.0f);
            const float x = ln.x * t + ln.z * (1.0f - t) - 0.5f;   // indexes H
            const float y = ln.y * t + ln.w * (1.0f - t) - 0.5f;   // indexes W
            const float x0f = fminf(fmaxf(floorf(x), 0.0f), 127.0f);
            const float y0f = fminf(fmaxf(floorf(y), 0.0f), 127.0f);
            const float x1f = fminf(x0f + 1.0f, 127.0f);
            const float y1f = fminf(y0f + 1.0f, 127.0f);
            const int x0 = (int)x0f, x1 = (int)x1f, y0 = (int)y0f, y1 = (int)y1f;
            const float wx1 = x - x0f, wx0 = x1f - x;
            const float wy1 = y - y0f, wy0 = y1f - y;
            const uint32_t u00 = *(const uint32_t*)(fb + ((x0 * 128 + y0) << 7));
            const uint32_t u01 = *(const uint32_t*)(fb + ((x0 * 128 + y1) << 7));
            const uint32_t u10 = *(const uint32_t*)(fb + ((x1 * 128 + y0) << 7));
            const uint32_t u11 = *(const uint32_t*)(fb + ((x1 * 128 + y1) << 7));
            const float w00 = wy0 * wx0, w01 = wy1 * wx0, w10 = wy0 * wx1, w11 = wy1 * wx1;
            const float a = bflo(u00) * w00 + bflo(u01) * w01 + bflo(u10) * w10 + bflo(u11) * w11;
            const float b = bfhi(u00) * w00 + bfhi(u01) * w01 + bfhi(u10) * w10 + bfhi(u11) * w11;
            m0 = fmaxf(m0, a);
            m1 = fmaxf(m1, b);
        }
        ps[lane * 16 + g]     = f2bf(m0);   // channel 2*lane
        ps[lane * 16 + 8 + g] = f2bf(m1);   // channel 2*lane+1
    }
    __syncthreads();
    // coalesced 2KB row write
    *(uint2*)(flat + (size_t)n * 1024 + tid * 4) = ((const uint2*)ps)[tid];
}

// ---------------- bf16 GEMM: in-block split-K (2 streams), R2 sync structure per stream --------------
// 512 threads = 8 waves: (wr,wc,ks); ks-stream handles K-half [ks*512, ks*512+512), 16 iters of BK=32.
// Streams stage into separate LDS buffers concurrently -> 2x in-flight staging per block.
// End: ks=1 accumulators pass through LDS (4 rounds), ks=0 adds and runs the epilogue.
// FUSE3=0: Co[m][n] = relu(sum_k A[m][k]*B[n][k] + bias[n])  (bf16 store)
// FUSE3=1: out3[m][j] += sum_n relu(...)[m][n] * W3[j][n]    (fp32 atomics; out3 pre-init with b3)

DEVI void stage_swz(const uint16_t* Ag, const uint16_t* Bg, int K, int ktAbs,
                    uint16_t* as, uint16_t* bs, int t256) {
#pragma unroll
    for (int i = 0; i < 2; ++i) {
        const int c = i * 256 + t256;          // 16B chunk 0..511; 4 slots per 64B row
        const int row = c >> 2, slot = c & 3;
        const int src = slot ^ ((row >> 1) & 3);   // involution (R7: conflict-free, coalescing-safe)
        async16(Ag + (size_t)row * K + ktAbs + src * 8, as + c * 8);
        async16(Bg + (size_t)row * K + ktAbs + src * 8, bs + c * 8);
    }
}

template <int FUSE3>
__global__ __launch_bounds__(512, 4) void gemm_bt(const uint16_t* __restrict__ A,
                                                  const uint16_t* __restrict__ B,
                                                  const float* __restrict__ bias,
                                                  uint16_t* __restrict__ Co,
                                                  const float* __restrict__ W3,
                                                  float* __restrict__ out3,
                                                  int M, int N, int K) {
    __shared__ uint16_t As[2][128 * 32];   // per-stream A buffer (8 KB each)
    __shared__ uint16_t Bs[2][128 * 32];   // per-stream B buffer
    const int tid = threadIdx.x;
    const int t256 = tid & 255;
    const int ks = tid >> 8;                       // K-stream 0/1
    const int lane = tid & 63;
    const int w2 = (tid >> 6) & 3;                 // wave-within-stream
    const int wr = w2 >> 1, wc = w2 & 1;           // 2x2 waves per stream, each 64x64
    const int l15 = lane & 15, l16 = lane >> 4;
    const int nbm = M >> 7;
    const int bm = blockIdx.x % nbm;               // bn-partners stride 64 (==0 mod 8): same XCD
    const int bn = blockIdx.x / nbm;

    f32x4 acc[4][4] = {};

    const uint16_t* Ag = A + (size_t)(bm * 128) * K;
    const uint16_t* Bg = B + (size_t)(bn * 128) * K;
    const int kbase = ks * (K >> 1);               // this stream's K-half

    for (int kt = 0; kt < (K >> 1); kt += 32) {
        if (kt) __syncthreads();
        stage_swz(Ag, Bg, K, kbase + kt, As[ks], Bs[ks], t256);
        __syncthreads();
        short8 a[4], b[4];
#pragma unroll
        for (int fm = 0; fm < 4; ++fm) {
            const int r = wr * 64 + fm * 16 + l15;
            a[fm] = *(const short8*)&As[ks][r * 32 + (l16 ^ ((r >> 1) & 3)) * 8];
        }
#pragma unroll
        for (int fn = 0; fn < 4; ++fn) {
            const int r = wc * 64 + fn * 16 + l15;
            b[fn] = *(const short8*)&Bs[ks][r * 32 + (l16 ^ ((r >> 1) & 3)) * 8];
        }
#pragma unroll
        for (int fm = 0; fm < 4; ++fm)
#pragma unroll
            for (int fn = 0; fn < 4; ++fn)
                acc[fm][fn] = __builtin_amdgcn_mfma_f32_16x16x32_bf16(a[fm], b[fn], acc[fm][fn], 0, 0, 0);
    }

    // ---- in-block K-reduce: ks=1 acc -> LDS (fp32), ks=0 adds. 4 rounds of 32x128 floats (16 KB) ----
    float* smemF = (float*)As;                     // As[2] = 16 KB = 4096 floats
#pragma unroll
    for (int fm = 0; fm < 4; ++fm) {
        __syncthreads();
        if (ks == 1) {
#pragma unroll
            for (int fn = 0; fn < 4; ++fn)
#pragma unroll
                for (int r = 0; r < 4; ++r)
                    smemF[(wr * 16 + l16 * 4 + r) * 128 + wc * 64 + fn * 16 + l15] = acc[fm][fn][r];
        }
        __syncthreads();
        if (ks == 0) {
#pragma unroll
            for (int fn = 0; fn < 4; ++fn)
#pragma unroll
                for (int r = 0; r < 4; ++r)
                    acc[fm][fn][r] += smemF[(wr * 16 + l16 * 4 + r) * 128 + wc * 64 + fn * 16 + l15];
        }
    }
    if (ks != 0) return;

    if (!FUSE3) {
#pragma unroll
        for (int fm = 0; fm < 4; ++fm) {
            const int row = bm * 128 + wr * 64 + fm * 16 + l16 * 4;
#pragma unroll
            for (int fn = 0; fn < 4; ++fn) {
                const int col = bn * 128 + wc * 64 + fn * 16 + l15;
                const float bv = bias[col];
#pragma unroll
                for (int r = 0; r < 4; ++r) {
                    float v = fmaxf(acc[fm][fn][r] + bv, 0.0f);
                    Co[(size_t)(row + r) * N + col] = f2bf(v);
                }
            }
        }
    } else {
        float bv[4], w3v[4][4];
#pragma unroll
        for (int fn = 0; fn < 4; ++fn) {
            const int col = bn * 128 + wc * 64 + fn * 16 + l15;
            bv[fn] = bias[col];
#pragma unroll
            for (int j = 0; j < 4; ++j) w3v[j][fn] = W3[j * N + col];
        }
#pragma unroll
        for (int fm = 0; fm < 4; ++fm) {
            const int row = bm * 128 + wr * 64 + fm * 16 + l16 * 4;
#pragma unroll
            for (int r = 0; r < 4; ++r) {
                float p[4] = { 0.0f, 0.0f, 0.0f, 0.0f };
#pragma unroll
                for (int fn = 0; fn < 4; ++fn) {
                    const float hv = fmaxf(acc[fm][fn][r] + bv[fn], 0.0f);
#pragma unroll
                    for (int j = 0; j < 4; ++j) p[j] += hv * w3v[j][fn];
                }
#pragma unroll
                for (int off = 1; off <= 8; off <<= 1)
#pragma unroll
                    for (int j = 0; j < 4; ++j) p[j] += __shfl_xor(p[j], off);
                if (l15 == 0) {
                    float* o = out3 + (size_t)(row + r) * 4;
#pragma unroll
                    for (int j = 0; j < 4; ++j) atomicAdd(o + j, p[j]);
                }
            }
        }
    }
}

extern "C" void kernel_launch(void* const* d_in, const int* in_sizes, int n_in,
                              void* d_out, int out_size, void* d_ws, size_t ws_size,
                              hipStream_t stream) {
    const float* feats = (const float*)d_in[0];   // 128*128*128 (C,H,W)
    const float* lines = (const float*)d_in[1];   // 8192*4
    const float* W1 = (const float*)d_in[2];      // 1024*1024
    const float* b1 = (const float*)d_in[3];
    const float* W2 = (const float*)d_in[4];
    const float* b2 = (const float*)d_in[5];
    const float* W3 = (const float*)d_in[6];      // 4*1024
    const float* b3 = (const float*)d_in[7];
    float* out = (float*)d_out;

    char* ws = (char*)d_ws;
    uint16_t* featT = (uint16_t*)(ws);                        // 4 MB  (H,W,C) bf16
    uint16_t* W1b   = (uint16_t*)(ws + (4u << 20));           // 2 MB
    uint16_t* W2b   = (uint16_t*)(ws + (6u << 20));           // 2 MB
    uint16_t* flat  = (uint16_t*)(ws + (8u << 20));           // 16 MB
    uint16_t* h1    = (uint16_t*)(ws + (24u << 20));          // 16 MB -> total 40 MB

    init_out<<<32, 256, 0, stream>>>(out, b3);
    prep_all<<<1152, 256, 0, stream>>>(feats, featT, W1, W1b, W2, W2b);
    extract_k<<<8192, 256, 0, stream>>>((const float4*)lines, featT, flat);
    gemm_bt<0><<<512, 512, 0, stream>>>(flat, W1b, b1, h1, nullptr, nullptr, 8192, 1024, 1024);
    gemm_bt<1><<<512, 512, 0, stream>>>(h1, W2b, b2, nullptr, W3, out, 8192, 1024, 1024);
}